// Round 2
// baseline (739.025 us; speedup 1.0000x reference)
//
#include <hip/hip_runtime.h>

// ---- degree histogram over dst (skip zero weights) ----
__global__ void k_deg(const int* __restrict__ ei, const float* __restrict__ ew,
                      int* __restrict__ deg, int E) {
    int e = blockIdx.x * 256 + threadIdx.x;
    if (e >= E) return;
    if (ew[e] != 0.0f) atomicAdd(&deg[ei[E + e]], 1);
}

// ---- exclusive scan of deg -> offs[N+1], single block of 1024 ----
__global__ void k_scan(const int* __restrict__ deg, int* __restrict__ offs, int n) {
    __shared__ int wsum[16];
    __shared__ int s_carry;
    int t = threadIdx.x;
    int lane = t & 63, wv = t >> 6;
    if (t == 0) s_carry = 0;
    __syncthreads();
    for (int base = 0; base < n; base += 1024) {
        int idx = base + t;
        int v = (idx < n) ? deg[idx] : 0;
        int s = v;
        #pragma unroll
        for (int off = 1; off < 64; off <<= 1) {
            int u = __shfl_up(s, off);
            if (lane >= off) s += u;
        }
        if (lane == 63) wsum[wv] = s;
        __syncthreads();
        if (t < 16) {
            int sv = wsum[t];
            #pragma unroll
            for (int off = 1; off < 16; off <<= 1) {
                int u = __shfl_up(sv, off);
                if (t >= off) sv += u;
            }
            wsum[t] = sv;
        }
        __syncthreads();
        int carry = s_carry;
        int wbase = wv ? wsum[wv - 1] : 0;
        if (idx < n) offs[idx] = carry + wbase + s - v;
        __syncthreads();
        if (t == 1023) s_carry = carry + wsum[15];
        __syncthreads();
    }
    if (t == 0) offs[n] = s_carry;
}

// ---- fill CSR: payload = src | (pos?bit31:0) ----
__global__ void k_fill(const int* __restrict__ ei, const float* __restrict__ ew,
                       const int* __restrict__ offs, int* __restrict__ cursor,
                       unsigned* __restrict__ csr, int E) {
    int e = blockIdx.x * 256 + threadIdx.x;
    if (e >= E) return;
    float w = ew[e];
    if (w == 0.0f) return;
    int src = ei[e];
    int dst = ei[E + e];
    int slot = offs[dst] + atomicAdd(&cursor[dst], 1);
    csr[slot] = (unsigned)src | (w > 0.0f ? 0x80000000u : 0u);
}

// ---- layer 1: wave-per-node. agg (lane=feature) -> LDS -> GEMV (lane=out col) ----
__global__ __launch_bounds__(256) void k_l1(
    const float* __restrict__ x, const int* __restrict__ offs, const unsigned* __restrict__ csr,
    const float* __restrict__ w1pl, const float* __restrict__ w1pr, const float* __restrict__ b1p,
    const float* __restrict__ w1nl, const float* __restrict__ w1nr, const float* __restrict__ b1n,
    float* __restrict__ h, int N)
{
    __shared__ float s_sp[4][64], s_sn[4][64], s_x[4][64];
    const int lane = threadIdx.x & 63;
    const int wv   = threadIdx.x >> 6;
    const int c    = lane & 31;
    const bool ng  = lane >= 32;

    // per-lane weight column in registers (amortized over grid-stride nodes)
    const float* WL = ng ? w1nl : w1pl;
    const float* WR = ng ? w1nr : w1pr;
    float wl[64], wr[64];
    #pragma unroll
    for (int k = 0; k < 64; ++k) {
        wl[k] = WL[k * 32 + c];
        wr[k] = WR[k * 32 + c];
    }
    const float bias = (ng ? b1n : b1p)[c];

    const int gw = blockIdx.x * 4 + wv;
    const int nw = gridDim.x * 4;
    for (int i = gw; i < N; i += nw) {
        float xv = x[(size_t)i * 64 + lane];
        int beg = offs[i], end = offs[i + 1];
        float sp = 0.f, sn = 0.f;
        int cp = 0, cn = 0;
        int t = beg;
        for (; t + 4 <= end; t += 4) {
            unsigned p0 = csr[t], p1 = csr[t + 1], p2 = csr[t + 2], p3 = csr[t + 3];
            float v0 = x[(size_t)(p0 & 0x7fffffffu) * 64 + lane];
            float v1 = x[(size_t)(p1 & 0x7fffffffu) * 64 + lane];
            float v2 = x[(size_t)(p2 & 0x7fffffffu) * 64 + lane];
            float v3 = x[(size_t)(p3 & 0x7fffffffu) * 64 + lane];
            if (p0 >> 31) { sp += v0; cp++; } else { sn += v0; cn++; }
            if (p1 >> 31) { sp += v1; cp++; } else { sn += v1; cn++; }
            if (p2 >> 31) { sp += v2; cp++; } else { sn += v2; cn++; }
            if (p3 >> 31) { sp += v3; cp++; } else { sn += v3; cn++; }
        }
        for (; t < end; ++t) {
            unsigned p0 = csr[t];
            float v0 = x[(size_t)(p0 & 0x7fffffffu) * 64 + lane];
            if (p0 >> 31) { sp += v0; cp++; } else { sn += v0; cn++; }
        }

        s_sp[wv][lane] = sp;
        s_sn[wv][lane] = sn;
        s_x [wv][lane] = xv;
        // same-wave LDS RAW: lockstep + compiler lgkmcnt waits
        float rp = 1.0f / fmaxf((float)cp, 1.0f);
        float rn = 1.0f / fmaxf((float)cn, 1.0f);
        const float* sa = ng ? s_sn[wv] : s_sp[wv];
        float acc = 0.f, accx = 0.f;
        #pragma unroll
        for (int k4 = 0; k4 < 16; ++k4) {
            float4 a4 = *reinterpret_cast<const float4*>(&sa[k4 * 4]);
            float4 x4 = *reinterpret_cast<const float4*>(&s_x[wv][k4 * 4]);
            acc  += a4.x * wl[k4*4] + a4.y * wl[k4*4+1] + a4.z * wl[k4*4+2] + a4.w * wl[k4*4+3];
            accx += x4.x * wr[k4*4] + x4.y * wr[k4*4+1] + x4.z * wr[k4*4+2] + x4.w * wr[k4*4+3];
        }
        float o = acc * (ng ? rn : rp) + accx + bias;
        h[(size_t)i * 64 + lane] = fmaxf(o, 0.f);
    }
}

// ---- layer 2: wave-per-node; a1..a4 folded into 2 accumulators via shfl_xor(32) ----
__global__ __launch_bounds__(256) void k_l2(
    const float* __restrict__ h, const int* __restrict__ offs, const unsigned* __restrict__ csr,
    const float* __restrict__ w2pl, const float* __restrict__ w2pr, const float* __restrict__ b2p,
    const float* __restrict__ w2nl, const float* __restrict__ w2nr, const float* __restrict__ b2n,
    float* __restrict__ out, int N)
{
    __shared__ float s_cat[4][2][64];   // [wave][pos/neg][k]
    __shared__ float s_h[4][64];
    const int lane = threadIdx.x & 63;
    const int wv   = threadIdx.x >> 6;
    const int c    = lane & 31;
    const bool ng  = lane >= 32;

    const float* W2L = ng ? w2nl : w2pl;   // (64,32)
    const float* W2R = ng ? w2nr : w2pr;   // (32,32)
    float wl[64], wr[32];
    #pragma unroll
    for (int k = 0; k < 64; ++k) wl[k] = W2L[k * 32 + c];
    #pragma unroll
    for (int k = 0; k < 32; ++k) wr[k] = W2R[k * 32 + c];
    const float bias = (ng ? b2n : b2p)[c];

    const int gw = blockIdx.x * 4 + wv;
    const int nw = gridDim.x * 4;
    for (int i = gw; i < N; i += nw) {
        float hv = h[(size_t)i * 64 + lane];
        int beg = offs[i], end = offs[i + 1];
        float accA = 0.f, accB = 0.f;   // lanes<32: a1,a2 ; lanes>=32: a3,a4
        int cp = 0, cn = 0;
        int t = beg;
        for (; t + 4 <= end; t += 4) {
            unsigned p0 = csr[t], p1 = csr[t + 1], p2 = csr[t + 2], p3 = csr[t + 3];
            float v0 = h[(size_t)(p0 & 0x7fffffffu) * 64 + lane];
            float v1 = h[(size_t)(p1 & 0x7fffffffu) * 64 + lane];
            float v2 = h[(size_t)(p2 & 0x7fffffffu) * 64 + lane];
            float v3 = h[(size_t)(p3 & 0x7fffffffu) * 64 + lane];
            // csr[t] is wave-uniform -> uniform branch, shfl is safe
            if (p0 >> 31) { accA += v0; cp++; } else { accB += __shfl_xor(v0, 32); cn++; }
            if (p1 >> 31) { accA += v1; cp++; } else { accB += __shfl_xor(v1, 32); cn++; }
            if (p2 >> 31) { accA += v2; cp++; } else { accB += __shfl_xor(v2, 32); cn++; }
            if (p3 >> 31) { accA += v3; cp++; } else { accB += __shfl_xor(v3, 32); cn++; }
        }
        for (; t < end; ++t) {
            unsigned p0 = csr[t];
            float v0 = h[(size_t)(p0 & 0x7fffffffu) * 64 + lane];
            if (p0 >> 31) { accA += v0; cp++; } else { accB += __shfl_xor(v0, 32); cn++; }
        }

        float rp = 1.0f / fmaxf((float)cp, 1.0f);
        float rn = 1.0f / fmaxf((float)cn, 1.0f);
        // lanes<32 own cat_p = [a1 || a2], lanes>=32 own cat_n = [a3 || a4]
        s_cat[wv][ng ? 1 : 0][c]      = accA * rp;
        s_cat[wv][ng ? 1 : 0][32 + c] = accB * rn;
        s_h[wv][lane] = hv;

        const float* cat  = s_cat[wv][ng ? 1 : 0];
        const float* hrow = &s_h[wv][ng ? 32 : 0];
        float acc = 0.f, acch = 0.f;
        #pragma unroll
        for (int k4 = 0; k4 < 16; ++k4) {
            float4 a4 = *reinterpret_cast<const float4*>(&cat[k4 * 4]);
            acc += a4.x * wl[k4*4] + a4.y * wl[k4*4+1] + a4.z * wl[k4*4+2] + a4.w * wl[k4*4+3];
        }
        #pragma unroll
        for (int k4 = 0; k4 < 8; ++k4) {
            float4 h4 = *reinterpret_cast<const float4*>(&hrow[k4 * 4]);
            acch += h4.x * wr[k4*4] + h4.y * wr[k4*4+1] + h4.z * wr[k4*4+2] + h4.w * wr[k4*4+3];
        }
        float o = acc + acch + bias;
        out[(size_t)i * 64 + lane] = fmaxf(o, 0.f);
    }
}

static inline size_t align512(size_t v) { return (v + 511) & ~(size_t)511; }

extern "C" void kernel_launch(void* const* d_in, const int* in_sizes, int n_in,
                              void* d_out, int out_size, void* d_ws, size_t ws_size,
                              hipStream_t stream) {
    const float* x    = (const float*)d_in[0];
    const int*   ei   = (const int*)d_in[1];     // [2][E] int32 (harness-converted)
    const float* ew   = (const float*)d_in[2];
    const float* w1pl = (const float*)d_in[3];
    const float* w1pr = (const float*)d_in[4];
    const float* b1p  = (const float*)d_in[5];
    const float* w1nl = (const float*)d_in[6];
    const float* w1nr = (const float*)d_in[7];
    const float* b1n  = (const float*)d_in[8];
    const float* w2pl = (const float*)d_in[9];
    const float* w2pr = (const float*)d_in[10];
    const float* b2p  = (const float*)d_in[11];
    const float* w2nl = (const float*)d_in[12];
    const float* w2nr = (const float*)d_in[13];
    const float* b2n  = (const float*)d_in[14];

    const int N = in_sizes[0] / 64;
    const int E = in_sizes[2];

    char* ws = (char*)d_ws;
    size_t o = 0;
    int* deg        = (int*)(ws + o);      o = align512(o + (size_t)N * 4);
    int* cursor     = (int*)(ws + o);      size_t zero_end = o + (size_t)N * 4;
                                           o = align512(zero_end);
    int* offs       = (int*)(ws + o);      o = align512(o + ((size_t)N + 1) * 4);
    unsigned* csr   = (unsigned*)(ws + o); o = align512(o + (size_t)E * 4);
    float* hbuf     = (float*)(ws + o);    // N*64*4 bytes

    hipMemsetAsync(d_ws, 0, zero_end, stream);   // deg, cursor

    k_deg  <<<(E + 255) / 256, 256, 0, stream>>>(ei, ew, deg, E);
    k_scan <<<1, 1024, 0, stream>>>(deg, offs, N);
    k_fill <<<(E + 255) / 256, 256, 0, stream>>>(ei, ew, offs, cursor, csr, E);
    k_l1   <<<2048, 256, 0, stream>>>(x, offs, csr, w1pl, w1pr, b1p, w1nl, w1nr, b1n, hbuf, N);
    k_l2   <<<2048, 256, 0, stream>>>(hbuf, offs, csr, w2pl, w2pr, b2p, w2nl, w2nr, b2n,
                                      (float*)d_out, N);
}

// Round 3
// 330.726 us; speedup vs baseline: 2.2346x; 2.2346x over previous
//
#include <hip/hip_runtime.h>
#include <hip/hip_fp16.h>

typedef unsigned int u32;

// ---------- helpers ----------
__device__ __forceinline__ void acc_half8(float acc[8], const uint4 d) {
    const __half2* h = reinterpret_cast<const __half2*>(&d);
    #pragma unroll
    for (int q = 0; q < 4; ++q) {
        float2 f = __half22float2(h[q]);
        acc[2*q]   += f.x;
        acc[2*q+1] += f.y;
    }
}
__device__ __forceinline__ uint4 pack_half8(const float v[8], float s) {
    uint4 r;
    u32* p = &r.x;
    #pragma unroll
    for (int q = 0; q < 4; ++q) {
        __half2 h = __float22half2_rn(make_float2(v[2*q] * s, v[2*q+1] * s));
        p[q] = *reinterpret_cast<const u32*>(&h);
    }
    return r;
}

// ---------- CSR build ----------
__global__ void k_deg(const int* __restrict__ ei, const float* __restrict__ ew,
                      int* __restrict__ degp, int* __restrict__ degn, int E) {
    int e = blockIdx.x * 256 + threadIdx.x;
    if (e >= E) return;
    float w = ew[e];
    if (w > 0.0f)      atomicAdd(&degp[ei[E + e]], 1);
    else if (w < 0.0f) atomicAdd(&degn[ei[E + e]], 1);
}

// tile-local exclusive scan of (degp+degn); tile totals to tsum
__global__ void k_scan_a(const int* __restrict__ degp, const int* __restrict__ degn,
                         int* __restrict__ offs, int* __restrict__ tsum, int n) {
    __shared__ int wsum[16];
    int t = threadIdx.x;
    int idx = blockIdx.x * 1024 + t;
    int lane = t & 63, wv = t >> 6;
    int v = (idx < n) ? degp[idx] + degn[idx] : 0;
    int s = v;
    #pragma unroll
    for (int off = 1; off < 64; off <<= 1) {
        int u = __shfl_up(s, off);
        if (lane >= off) s += u;
    }
    if (lane == 63) wsum[wv] = s;
    __syncthreads();
    if (t < 16) {
        int sv = wsum[t];
        #pragma unroll
        for (int off = 1; off < 16; off <<= 1) {
            int u = __shfl_up(sv, off);
            if (t >= off) sv += u;
        }
        wsum[t] = sv;
    }
    __syncthreads();
    int wbase = wv ? wsum[wv - 1] : 0;
    if (idx < n) offs[idx] = wbase + s - v;
    if (t == 1023) tsum[blockIdx.x] = wbase + s;
}

// scan tile totals (nb <= 128), write grand total to *offs_n
__global__ void k_scan_b(int* __restrict__ tsum, int* __restrict__ offs_n, int nb) {
    __shared__ int w0tot;
    int t = threadIdx.x;
    int v = (t < nb) ? tsum[t] : 0;
    int s = v;
    #pragma unroll
    for (int off = 1; off < 64; off <<= 1) {
        int u = __shfl_up(s, off);
        if ((t & 63) >= off) s += u;
    }
    if (t == 63) w0tot = s;
    __syncthreads();
    int excl = s - v + (t >= 64 ? w0tot : 0);
    if (t < nb) tsum[t] = excl;
    if (t == nb - 1) *offs_n = excl + v;
}

// add tile bases; compute posend and reciprocal counts
__global__ void k_scan_c(int* __restrict__ offs, const int* __restrict__ tsum,
                         const int* __restrict__ degp, const int* __restrict__ degn,
                         int* __restrict__ posend, float* __restrict__ rp, float* __restrict__ rn, int n) {
    int idx = blockIdx.x * 1024 + threadIdx.x;
    if (idx >= n) return;
    int o = offs[idx] + tsum[idx >> 10];
    int dp = degp[idx], dn = degn[idx];
    offs[idx]   = o;
    posend[idx] = o + dp;
    rp[idx] = 1.0f / (float)max(dp, 1);
    rn[idx] = 1.0f / (float)max(dn, 1);
}

__global__ void k_fill(const int* __restrict__ ei, const float* __restrict__ ew,
                       const int* __restrict__ offs, const int* __restrict__ posend,
                       int* __restrict__ cursp, int* __restrict__ cursn,
                       u32* __restrict__ csr, int E) {
    int e = blockIdx.x * 256 + threadIdx.x;
    if (e >= E) return;
    float w = ew[e];
    if (w == 0.0f) return;
    int src = ei[e], dst = ei[E + e];
    int slot;
    if (w > 0.0f) slot = offs[dst]   + atomicAdd(&cursp[dst], 1);
    else          slot = posend[dst] + atomicAdd(&cursn[dst], 1);
    csr[slot] = (u32)src;
}

// ---------- dense transform 1: z1 = x@[w1pl||w1nl], xr = x@[w1pr||w1nr]+bias (fp16 out) ----------
__global__ __launch_bounds__(256) void k_gemm1(
    const float* __restrict__ x,
    const float* __restrict__ w1pl, const float* __restrict__ w1pr, const float* __restrict__ b1p,
    const float* __restrict__ w1nl, const float* __restrict__ w1nr, const float* __restrict__ b1n,
    __half* __restrict__ z1, __half* __restrict__ xr, int N)
{
    __shared__ float s_x[4][64];
    const int lane = threadIdx.x & 63;
    const int wv   = threadIdx.x >> 6;
    const int c    = lane & 31;
    const bool ng  = lane >= 32;
    const float* WL = ng ? w1nl : w1pl;
    const float* WR = ng ? w1nr : w1pr;
    float wl[64], wr[64];
    #pragma unroll
    for (int k = 0; k < 64; ++k) {
        wl[k] = WL[k * 32 + c];
        wr[k] = WR[k * 32 + c];
    }
    const float bias = (ng ? b1n : b1p)[c];

    const int gw = blockIdx.x * 4 + wv;
    const int nw = gridDim.x * 4;
    for (int i = gw; i < N; i += nw) {
        s_x[wv][lane] = x[(size_t)i * 64 + lane];
        float az = 0.f, ar = bias;
        #pragma unroll
        for (int k4 = 0; k4 < 16; ++k4) {
            float4 xx = *reinterpret_cast<const float4*>(&s_x[wv][k4 * 4]);
            az += xx.x * wl[k4*4] + xx.y * wl[k4*4+1] + xx.z * wl[k4*4+2] + xx.w * wl[k4*4+3];
            ar += xx.x * wr[k4*4] + xx.y * wr[k4*4+1] + xx.z * wr[k4*4+2] + xx.w * wr[k4*4+3];
        }
        z1[(size_t)i * 64 + lane] = __float2half(az);
        xr[(size_t)i * 64 + lane] = __float2half(ar);
    }
}

// ---------- gather 1: h = relu(xr + [mean_p(xp) || mean_n(xn)]) ----------
// row halves are 64B; 4 lanes x 16B per row; 8 pos rows + 8 neg rows per batch, unroll 2
__global__ __launch_bounds__(256) void k_g1(
    const __half* __restrict__ z1, const __half* __restrict__ xr,
    const int* __restrict__ offs, const int* __restrict__ posend,
    const float* __restrict__ rpb, const float* __restrict__ rnb,
    const u32* __restrict__ csr, __half* __restrict__ h, int N)
{
    const int lane = threadIdx.x & 63;
    const int wv   = threadIdx.x >> 6;
    const int side = lane >> 5;            // 0: pos edges, 1: neg edges
    const int g    = (lane & 31) >> 2;     // 0..7 row group
    const int j    = lane & 3;             // 16B slice within 64B half-row
    const int hOff = side ? 32 : 0;

    const int gw = blockIdx.x * 4 + wv;
    const int nw = gridDim.x * 4;
    for (int i = gw; i < N; i += nw) {
        int beg = offs[i], pend = posend[i], end = offs[i + 1];
        int t    = (side ? pend : beg) + g;
        int send = side ? end : pend;
        float acc[8] = {0,0,0,0,0,0,0,0};
        while (t < send) {
            u32 s0 = csr[t];
            uint4 d0 = *reinterpret_cast<const uint4*>(z1 + (size_t)s0 * 64 + hOff + j * 8);
            int t1 = t + 8;
            if (t1 < send) {
                u32 s1 = csr[t1];
                uint4 d1 = *reinterpret_cast<const uint4*>(z1 + (size_t)s1 * 64 + hOff + j * 8);
                acc_half8(acc, d0);
                acc_half8(acc, d1);
            } else {
                acc_half8(acc, d0);
            }
            t += 16;
        }
        #pragma unroll
        for (int m = 4; m <= 16; m <<= 1)
            #pragma unroll
            for (int q = 0; q < 8; ++q) acc[q] += __shfl_xor(acc[q], m);

        int wl = lane & 31;
        if (wl < 4) {                      // 4 writer lanes per side
            float sc = side ? rnb[i] : rpb[i];
            uint4 xd = *reinterpret_cast<const uint4*>(xr + (size_t)i * 64 + hOff + wl * 8);
            const __half2* xh = reinterpret_cast<const __half2*>(&xd);
            float out[8];
            #pragma unroll
            for (int q = 0; q < 4; ++q) {
                float2 f = __half22float2(xh[q]);
                out[2*q]   = fmaxf(f.x + acc[2*q]   * sc, 0.f);
                out[2*q+1] = fmaxf(f.y + acc[2*q+1] * sc, 0.f);
            }
            *reinterpret_cast<uint4*>(h + (size_t)i * 64 + hOff + wl * 8) = pack_half8(out, 1.f);
        }
    }
}

// ---------- gather 2a: cat = [a1|a2|a3|a4] means (fp16) ----------
// h rows are 128B; 8 lanes x 16B per row; 4 pos + 4 neg rows per batch, unroll 2
__global__ __launch_bounds__(256) void k_g2a(
    const __half* __restrict__ h,
    const int* __restrict__ offs, const int* __restrict__ posend,
    const float* __restrict__ rpb, const float* __restrict__ rnb,
    const u32* __restrict__ csr, __half* __restrict__ cat, int N)
{
    const int lane = threadIdx.x & 63;
    const int wv   = threadIdx.x >> 6;
    const int side = lane >> 5;
    const int g    = (lane & 31) >> 3;     // 0..3
    const int j    = lane & 7;             // 16B slice of 128B row

    const int gw = blockIdx.x * 4 + wv;
    const int nw = gridDim.x * 4;
    for (int i = gw; i < N; i += nw) {
        int beg = offs[i], pend = posend[i], end = offs[i + 1];
        int t    = (side ? pend : beg) + g;
        int send = side ? end : pend;
        float acc[8] = {0,0,0,0,0,0,0,0};
        while (t < send) {
            u32 s0 = csr[t];
            uint4 d0 = *reinterpret_cast<const uint4*>(h + (size_t)s0 * 64 + j * 8);
            int t1 = t + 4;
            if (t1 < send) {
                u32 s1 = csr[t1];
                uint4 d1 = *reinterpret_cast<const uint4*>(h + (size_t)s1 * 64 + j * 8);
                acc_half8(acc, d0);
                acc_half8(acc, d1);
            } else {
                acc_half8(acc, d0);
            }
            t += 8;
        }
        #pragma unroll
        for (int m = 8; m <= 16; m <<= 1)
            #pragma unroll
            for (int q = 0; q < 8; ++q) acc[q] += __shfl_xor(acc[q], m);

        int wl = lane & 31;
        if (wl < 8) {                      // 8 writer lanes per side
            float sc = side ? rnb[i] : rpb[i];
            // pos side holds [mean_p(hp)=a1 || mean_p(hn)=a3]; neg side [mean_n(hp)=a4 || mean_n(hn)=a2]
            int off = side ? (wl < 4 ? 96 + wl * 8 : 32 + (wl - 4) * 8)
                           : (wl < 4 ? wl * 8      : 64 + (wl - 4) * 8);
            *reinterpret_cast<uint4*>(cat + (size_t)i * 128 + off) = pack_half8(acc, sc);
        }
    }
}

// ---------- gather 2b: out = relu(cat@W2L + h@W2R + b) ----------
__global__ __launch_bounds__(256) void k_g2b(
    const __half* __restrict__ cat, const __half* __restrict__ h,
    const float* __restrict__ w2pl, const float* __restrict__ w2pr, const float* __restrict__ b2p,
    const float* __restrict__ w2nl, const float* __restrict__ w2nr, const float* __restrict__ b2n,
    float* __restrict__ out, int N)
{
    __shared__ float s_c[4][128];
    __shared__ float s_h[4][64];
    const int lane = threadIdx.x & 63;
    const int wv   = threadIdx.x >> 6;
    const int c    = lane & 31;
    const bool ng  = lane >= 32;
    const float* WL = ng ? w2nl : w2pl;   // (64,32)
    const float* WR = ng ? w2nr : w2pr;   // (32,32)
    float wl[64], wr[32];
    #pragma unroll
    for (int k = 0; k < 64; ++k) wl[k] = WL[k * 32 + c];
    #pragma unroll
    for (int k = 0; k < 32; ++k) wr[k] = WR[k * 32 + c];
    const float bias = (ng ? b2n : b2p)[c];

    const int gw = blockIdx.x * 4 + wv;
    const int nw = gridDim.x * 4;
    for (int i = gw; i < N; i += nw) {
        {
            u32 u = reinterpret_cast<const u32*>(cat + (size_t)i * 128)[lane];
            __half2 hh = *reinterpret_cast<const __half2*>(&u);
            float2 f = __half22float2(hh);
            s_c[wv][2 * lane] = f.x;
            s_c[wv][2 * lane + 1] = f.y;
            if (lane < 32) {
                u32 u2 = reinterpret_cast<const u32*>(h + (size_t)i * 64)[lane];
                __half2 h2 = *reinterpret_cast<const __half2*>(&u2);
                float2 f2 = __half22float2(h2);
                s_h[wv][2 * lane] = f2.x;
                s_h[wv][2 * lane + 1] = f2.y;
            }
        }
        const float* C = &s_c[wv][ng ? 64 : 0];
        const float* H = &s_h[wv][ng ? 32 : 0];
        float acc = bias;
        #pragma unroll
        for (int k4 = 0; k4 < 16; ++k4) {
            float4 cc = *reinterpret_cast<const float4*>(&C[k4 * 4]);
            acc += cc.x * wl[k4*4] + cc.y * wl[k4*4+1] + cc.z * wl[k4*4+2] + cc.w * wl[k4*4+3];
        }
        #pragma unroll
        for (int k4 = 0; k4 < 8; ++k4) {
            float4 hh4 = *reinterpret_cast<const float4*>(&H[k4 * 4]);
            acc += hh4.x * wr[k4*4] + hh4.y * wr[k4*4+1] + hh4.z * wr[k4*4+2] + hh4.w * wr[k4*4+3];
        }
        out[(size_t)i * 64 + lane] = fmaxf(acc, 0.f);
    }
}

static inline size_t align512(size_t v) { return (v + 511) & ~(size_t)511; }

extern "C" void kernel_launch(void* const* d_in, const int* in_sizes, int n_in,
                              void* d_out, int out_size, void* d_ws, size_t ws_size,
                              hipStream_t stream) {
    const float* x    = (const float*)d_in[0];
    const int*   ei   = (const int*)d_in[1];
    const float* ew   = (const float*)d_in[2];
    const float* w1pl = (const float*)d_in[3];
    const float* w1pr = (const float*)d_in[4];
    const float* b1p  = (const float*)d_in[5];
    const float* w1nl = (const float*)d_in[6];
    const float* w1nr = (const float*)d_in[7];
    const float* b1n  = (const float*)d_in[8];
    const float* w2pl = (const float*)d_in[9];
    const float* w2pr = (const float*)d_in[10];
    const float* b2p  = (const float*)d_in[11];
    const float* w2nl = (const float*)d_in[12];
    const float* w2nr = (const float*)d_in[13];
    const float* b2n  = (const float*)d_in[14];

    const int N = in_sizes[0] / 64;
    const int E = in_sizes[2];
    const int NB = (N + 1023) / 1024;     // scan tiles (<=128)

    char* ws = (char*)d_ws;
    size_t o = 0;
    int* degp    = (int*)(ws + o);      o += (size_t)N * 4;
    int* degn    = (int*)(ws + o);      o += (size_t)N * 4;
    int* cursp   = (int*)(ws + o);      o += (size_t)N * 4;
    int* cursn   = (int*)(ws + o);      size_t zero_end = o + (size_t)N * 4;
                                        o = align512(zero_end);
    int* offs    = (int*)(ws + o);      o = align512(o + ((size_t)N + 1) * 4);
    int* pend    = (int*)(ws + o);      o = align512(o + (size_t)N * 4);
    float* rp    = (float*)(ws + o);    o = align512(o + (size_t)N * 4);
    float* rn    = (float*)(ws + o);    o = align512(o + (size_t)N * 4);
    int* tsum    = (int*)(ws + o);      o = align512(o + 512);
    u32* csr     = (u32*)(ws + o);      o = align512(o + (size_t)E * 4);
    __half* z1   = (__half*)(ws + o);   o = align512(o + (size_t)N * 64 * 2);
    __half* xr   = (__half*)(ws + o);   o = align512(o + (size_t)N * 64 * 2);
    __half* hbuf = (__half*)(ws + o);   o = align512(o + (size_t)N * 64 * 2);
    __half* cat  = (__half*)(ws + o);   // N*128*2 bytes (~67 MB total workspace)

    hipMemsetAsync(d_ws, 0, zero_end, stream);   // degp, degn, cursp, cursn

    k_deg   <<<(E + 255) / 256, 256, 0, stream>>>(ei, ew, degp, degn, E);
    k_scan_a<<<NB, 1024, 0, stream>>>(degp, degn, offs, tsum, N);
    k_scan_b<<<1, 128, 0, stream>>>(tsum, offs + N, NB);
    k_scan_c<<<NB, 1024, 0, stream>>>(offs, tsum, degp, degn, pend, rp, rn, N);
    k_fill  <<<(E + 255) / 256, 256, 0, stream>>>(ei, ew, offs, pend, cursp, cursn, csr, E);
    k_gemm1 <<<1024, 256, 0, stream>>>(x, w1pl, w1pr, b1p, w1nl, w1nr, b1n, z1, xr, N);
    k_g1    <<<2048, 256, 0, stream>>>(z1, xr, offs, pend, rp, rn, csr, hbuf, N);
    k_g2a   <<<2048, 256, 0, stream>>>(hbuf, offs, pend, rp, rn, csr, cat, N);
    k_g2b   <<<1024, 256, 0, stream>>>(cat, hbuf, w2pl, w2pr, b2p, w2nl, w2nr, b2n,
                                       (float*)d_out, N);
}

// Round 4
// 217.686 us; speedup vs baseline: 3.3949x; 1.5193x over previous
//
#include <hip/hip_runtime.h>
#include <hip/hip_fp16.h>

typedef unsigned int u32;

#define BSHIFT 8                    // 256 nodes per bucket
#define BMASK  255

// ---------- helpers ----------
__device__ __forceinline__ void acc_half8(float acc[8], const uint4 d) {
    const __half2* h = reinterpret_cast<const __half2*>(&d);
    #pragma unroll
    for (int q = 0; q < 4; ++q) {
        float2 f = __half22float2(h[q]);
        acc[2*q]   += f.x;
        acc[2*q+1] += f.y;
    }
}
__device__ __forceinline__ uint4 pack_half8(const float v[8], float s) {
    uint4 r;
    u32* p = &r.x;
    #pragma unroll
    for (int q = 0; q < 4; ++q) {
        __half2 h = __float22half2_rn(make_float2(v[2*q] * s, v[2*q+1] * s));
        p[q] = *reinterpret_cast<const u32*>(&h);
    }
    return r;
}

// ---------- 1) bucket counts (LDS-aggregated) ----------
__global__ __launch_bounds__(512) void k_bcnt(const int* __restrict__ ei, const float* __restrict__ ew,
                                              int* __restrict__ bcnt, int E, int nb) {
    __shared__ int lc[512];
    for (int i = threadIdx.x; i < nb; i += 512) lc[i] = 0;
    __syncthreads();
    const int stride = gridDim.x * 512;
    for (int e = blockIdx.x * 512 + threadIdx.x; e < E; e += stride) {
        float w = ew[e];
        if (w != 0.0f) atomicAdd(&lc[ei[E + e] >> BSHIFT], 1);
    }
    __syncthreads();
    for (int i = threadIdx.x; i < nb; i += 512) {
        int c = lc[i];
        if (c) atomicAdd(&bcnt[i], c);
    }
}

// ---------- 2) scan bucket counts -> bbase[nb+1], offs[N]=total ----------
__global__ __launch_bounds__(512) void k_bscan(const int* __restrict__ bcnt, int* __restrict__ bbase,
                                               int* __restrict__ offs_n, int nb) {
    __shared__ int wsum[8];
    const int t = threadIdx.x;
    const int lane = t & 63, wv = t >> 6;
    int v = (t < nb) ? bcnt[t] : 0;
    int s = v;
    #pragma unroll
    for (int off = 1; off < 64; off <<= 1) {
        int u = __shfl_up(s, off);
        if (lane >= off) s += u;
    }
    if (lane == 63) wsum[wv] = s;
    __syncthreads();
    if (t < 8) {
        int sv = wsum[t];
        #pragma unroll
        for (int off = 1; off < 8; off <<= 1) {
            int u = __shfl_up(sv, off);
            if (t >= off) sv += u;
        }
        wsum[t] = sv;
    }
    __syncthreads();
    int base = (wv ? wsum[wv - 1] : 0) + s - v;
    if (t < nb) bbase[t] = base;
    if (t == nb - 1) {
        bbase[nb] = base + v;
        *offs_n   = base + v;
    }
}

// ---------- 3) multi-split scatter into exact bucket regions ----------
#define BIN_T 512
#define BIN_K 16
__global__ __launch_bounds__(BIN_T) void k_bin(const int* __restrict__ ei, const float* __restrict__ ew,
                                               const int* __restrict__ bbase, int* __restrict__ gcur,
                                               u32* __restrict__ stage, int E, int nb) {
    __shared__ int lcnt[512];
    __shared__ int lbase[512];
    const int t = threadIdx.x;
    const int chunk = BIN_T * BIN_K;
    for (int c0 = blockIdx.x * chunk; c0 < E; c0 += gridDim.x * chunk) {
        for (int i = t; i < nb; i += BIN_T) lcnt[i] = 0;
        __syncthreads();
        u32 ent[BIN_K];
        int bk[BIN_K], loc[BIN_K];
        #pragma unroll
        for (int k = 0; k < BIN_K; ++k) {
            int e = c0 + k * BIN_T + t;
            bk[k] = -1;
            if (e < E) {
                float w = ew[e];
                if (w != 0.0f) {
                    int src = ei[e], dst = ei[E + e];
                    int b = dst >> BSHIFT;
                    bk[k]  = b;
                    ent[k] = (u32)src | ((u32)(dst & BMASK) << 17) | (w < 0.0f ? (1u << 25) : 0u);
                    loc[k] = atomicAdd(&lcnt[b], 1);
                }
            }
        }
        __syncthreads();
        for (int i = t; i < nb; i += BIN_T) {
            int c = lcnt[i];
            lbase[i] = c ? atomicAdd(&gcur[i], c) : 0;
        }
        __syncthreads();
        #pragma unroll
        for (int k = 0; k < BIN_K; ++k) {
            if (bk[k] >= 0) {
                int b = bk[k];
                stage[bbase[b] + lbase[b] + loc[k]] = ent[k];
            }
        }
        __syncthreads();
    }
}

// ---------- 4) per-bucket sort: csr + offs/pend/rp/rn ----------
__global__ __launch_bounds__(256) void k_sort(const u32* __restrict__ stage, const int* __restrict__ bbase,
                                              u32* __restrict__ csr,
                                              int* __restrict__ offs, int* __restrict__ pend,
                                              float* __restrict__ rp, float* __restrict__ rn,
                                              int N) {
    __shared__ int cnt[512];
    __shared__ int cbase[512];
    __shared__ int cur[512];
    const int b  = blockIdx.x;
    const int rb = bbase[b], re = bbase[b + 1];
    const int t  = threadIdx.x;
    cnt[t] = 0;
    cnt[t + 256] = 0;
    __syncthreads();
    // pass 1: count per (node,sign)
    for (int i = rb + t; i < re; i += 256) {
        u32 en = stage[i];
        atomicAdd(&cnt[((en >> 17) & BMASK) * 2 + ((en >> 25) & 1)], 1);
    }
    __syncthreads();
    // exclusive scan of 512 counters (wave 0, 8 per lane)
    if (t < 64) {
        int loc[8];
        int s = 0;
        #pragma unroll
        for (int q = 0; q < 8; ++q) { loc[q] = s; s += cnt[t * 8 + q]; }
        int tot = s;
        #pragma unroll
        for (int off = 1; off < 64; off <<= 1) {
            int u = __shfl_up(tot, off);
            if (t >= off) tot += u;
        }
        int excl = tot - s;
        #pragma unroll
        for (int q = 0; q < 8; ++q) {
            cbase[t * 8 + q] = excl + loc[q];
            cur  [t * 8 + q] = excl + loc[q];
        }
    }
    __syncthreads();
    // per-node outputs
    const int gn = (b << BSHIFT) + t;
    if (gn < N) {
        int cp = cnt[2 * t], cng = cnt[2 * t + 1];
        int o  = rb + cbase[2 * t];
        offs[gn] = o;
        pend[gn] = o + cp;
        rp[gn] = 1.0f / (float)max(cp, 1);
        rn[gn] = 1.0f / (float)max(cng, 1);
    }
    // pass 2: place (scatter within 16KB region -> L2-local)
    for (int i = rb + t; i < re; i += 256) {
        u32 en  = stage[i];
        int key = ((en >> 17) & BMASK) * 2 + ((en >> 25) & 1);
        int slot = rb + atomicAdd(&cur[key], 1);
        csr[slot] = en & 0x1FFFFu;
    }
}

// ---------- dense transform 1: z1 = x@[w1pl||w1nl], xr = x@[w1pr||w1nr]+bias (fp16) ----------
__global__ __launch_bounds__(256) void k_gemm1(
    const float* __restrict__ x,
    const float* __restrict__ w1pl, const float* __restrict__ w1pr, const float* __restrict__ b1p,
    const float* __restrict__ w1nl, const float* __restrict__ w1nr, const float* __restrict__ b1n,
    __half* __restrict__ z1, __half* __restrict__ xr, int N)
{
    __shared__ float s_x[4][64];
    const int lane = threadIdx.x & 63;
    const int wv   = threadIdx.x >> 6;
    const int c    = lane & 31;
    const bool ng  = lane >= 32;
    const float* WL = ng ? w1nl : w1pl;
    const float* WR = ng ? w1nr : w1pr;
    float wl[64], wr[64];
    #pragma unroll
    for (int k = 0; k < 64; ++k) {
        wl[k] = WL[k * 32 + c];
        wr[k] = WR[k * 32 + c];
    }
    const float bias = (ng ? b1n : b1p)[c];

    const int gw = blockIdx.x * 4 + wv;
    const int nw = gridDim.x * 4;
    for (int i = gw; i < N; i += nw) {
        s_x[wv][lane] = x[(size_t)i * 64 + lane];
        float az = 0.f, ar = bias;
        #pragma unroll
        for (int k4 = 0; k4 < 16; ++k4) {
            float4 xx = *reinterpret_cast<const float4*>(&s_x[wv][k4 * 4]);
            az += xx.x * wl[k4*4] + xx.y * wl[k4*4+1] + xx.z * wl[k4*4+2] + xx.w * wl[k4*4+3];
            ar += xx.x * wr[k4*4] + xx.y * wr[k4*4+1] + xx.z * wr[k4*4+2] + xx.w * wr[k4*4+3];
        }
        z1[(size_t)i * 64 + lane] = __float2half(az);
        xr[(size_t)i * 64 + lane] = __float2half(ar);
    }
}

// ---------- gather 1: h = relu(xr + [mean_p || mean_n]) ----------
__global__ __launch_bounds__(256) void k_g1(
    const __half* __restrict__ z1, const __half* __restrict__ xr,
    const int* __restrict__ offs, const int* __restrict__ posend,
    const float* __restrict__ rpb, const float* __restrict__ rnb,
    const u32* __restrict__ csr, __half* __restrict__ h, int N)
{
    const int lane = threadIdx.x & 63;
    const int wv   = threadIdx.x >> 6;
    const int side = lane >> 5;
    const int g    = (lane & 31) >> 2;
    const int j    = lane & 3;
    const int hOff = side ? 32 : 0;

    const int gw = blockIdx.x * 4 + wv;
    const int nw = gridDim.x * 4;
    for (int i = gw; i < N; i += nw) {
        int beg = offs[i], pend_ = posend[i], end = offs[i + 1];
        int t    = (side ? pend_ : beg) + g;
        int send = side ? end : pend_;
        float acc[8] = {0,0,0,0,0,0,0,0};
        while (t < send) {
            u32 s0 = csr[t];
            uint4 d0 = *reinterpret_cast<const uint4*>(z1 + (size_t)s0 * 64 + hOff + j * 8);
            int t1 = t + 8;
            if (t1 < send) {
                u32 s1 = csr[t1];
                uint4 d1 = *reinterpret_cast<const uint4*>(z1 + (size_t)s1 * 64 + hOff + j * 8);
                acc_half8(acc, d0);
                acc_half8(acc, d1);
            } else {
                acc_half8(acc, d0);
            }
            t += 16;
        }
        #pragma unroll
        for (int m = 4; m <= 16; m <<= 1)
            #pragma unroll
            for (int q = 0; q < 8; ++q) acc[q] += __shfl_xor(acc[q], m);

        int wl = lane & 31;
        if (wl < 4) {
            float sc = side ? rnb[i] : rpb[i];
            uint4 xd = *reinterpret_cast<const uint4*>(xr + (size_t)i * 64 + hOff + wl * 8);
            const __half2* xh = reinterpret_cast<const __half2*>(&xd);
            float out[8];
            #pragma unroll
            for (int q = 0; q < 4; ++q) {
                float2 f = __half22float2(xh[q]);
                out[2*q]   = fmaxf(f.x + acc[2*q]   * sc, 0.f);
                out[2*q+1] = fmaxf(f.y + acc[2*q+1] * sc, 0.f);
            }
            *reinterpret_cast<uint4*>(h + (size_t)i * 64 + hOff + wl * 8) = pack_half8(out, 1.f);
        }
    }
}

// ---------- gather 2a: cat = [a1|a2|a3|a4] means (fp16) ----------
__global__ __launch_bounds__(256) void k_g2a(
    const __half* __restrict__ h,
    const int* __restrict__ offs, const int* __restrict__ posend,
    const float* __restrict__ rpb, const float* __restrict__ rnb,
    const u32* __restrict__ csr, __half* __restrict__ cat, int N)
{
    const int lane = threadIdx.x & 63;
    const int wv   = threadIdx.x >> 6;
    const int side = lane >> 5;
    const int g    = (lane & 31) >> 3;
    const int j    = lane & 7;

    const int gw = blockIdx.x * 4 + wv;
    const int nw = gridDim.x * 4;
    for (int i = gw; i < N; i += nw) {
        int beg = offs[i], pend_ = posend[i], end = offs[i + 1];
        int t    = (side ? pend_ : beg) + g;
        int send = side ? end : pend_;
        float acc[8] = {0,0,0,0,0,0,0,0};
        while (t < send) {
            u32 s0 = csr[t];
            uint4 d0 = *reinterpret_cast<const uint4*>(h + (size_t)s0 * 64 + j * 8);
            int t1 = t + 4;
            if (t1 < send) {
                u32 s1 = csr[t1];
                uint4 d1 = *reinterpret_cast<const uint4*>(h + (size_t)s1 * 64 + j * 8);
                acc_half8(acc, d0);
                acc_half8(acc, d1);
            } else {
                acc_half8(acc, d0);
            }
            t += 8;
        }
        #pragma unroll
        for (int m = 8; m <= 16; m <<= 1)
            #pragma unroll
            for (int q = 0; q < 8; ++q) acc[q] += __shfl_xor(acc[q], m);

        int wl = lane & 31;
        if (wl < 8) {
            float sc = side ? rnb[i] : rpb[i];
            int off = side ? (wl < 4 ? 96 + wl * 8 : 32 + (wl - 4) * 8)
                           : (wl < 4 ? wl * 8      : 64 + (wl - 4) * 8);
            *reinterpret_cast<uint4*>(cat + (size_t)i * 128 + off) = pack_half8(acc, sc);
        }
    }
}

// ---------- gather 2b: out = relu(cat@W2L + h@W2R + b) ----------
__global__ __launch_bounds__(256) void k_g2b(
    const __half* __restrict__ cat, const __half* __restrict__ h,
    const float* __restrict__ w2pl, const float* __restrict__ w2pr, const float* __restrict__ b2p,
    const float* __restrict__ w2nl, const float* __restrict__ w2nr, const float* __restrict__ b2n,
    float* __restrict__ out, int N)
{
    __shared__ float s_c[4][128];
    __shared__ float s_h[4][64];
    const int lane = threadIdx.x & 63;
    const int wv   = threadIdx.x >> 6;
    const int c    = lane & 31;
    const bool ng  = lane >= 32;
    const float* WL = ng ? w2nl : w2pl;
    const float* WR = ng ? w2nr : w2pr;
    float wl[64], wr[32];
    #pragma unroll
    for (int k = 0; k < 64; ++k) wl[k] = WL[k * 32 + c];
    #pragma unroll
    for (int k = 0; k < 32; ++k) wr[k] = WR[k * 32 + c];
    const float bias = (ng ? b2n : b2p)[c];

    const int gw = blockIdx.x * 4 + wv;
    const int nw = gridDim.x * 4;
    for (int i = gw; i < N; i += nw) {
        {
            u32 u = reinterpret_cast<const u32*>(cat + (size_t)i * 128)[lane];
            __half2 hh = *reinterpret_cast<const __half2*>(&u);
            float2 f = __half22float2(hh);
            s_c[wv][2 * lane]     = f.x;
            s_c[wv][2 * lane + 1] = f.y;
            if (lane < 32) {
                u32 u2 = reinterpret_cast<const u32*>(h + (size_t)i * 64)[lane];
                __half2 h2 = *reinterpret_cast<const __half2*>(&u2);
                float2 f2 = __half22float2(h2);
                s_h[wv][2 * lane]     = f2.x;
                s_h[wv][2 * lane + 1] = f2.y;
            }
        }
        const float* C = &s_c[wv][ng ? 64 : 0];
        const float* H = &s_h[wv][ng ? 32 : 0];
        float acc = bias;
        #pragma unroll
        for (int k4 = 0; k4 < 16; ++k4) {
            float4 cc = *reinterpret_cast<const float4*>(&C[k4 * 4]);
            acc += cc.x * wl[k4*4] + cc.y * wl[k4*4+1] + cc.z * wl[k4*4+2] + cc.w * wl[k4*4+3];
        }
        #pragma unroll
        for (int k4 = 0; k4 < 8; ++k4) {
            float4 hh4 = *reinterpret_cast<const float4*>(&H[k4 * 4]);
            acc += hh4.x * wr[k4*4] + hh4.y * wr[k4*4+1] + hh4.z * wr[k4*4+2] + hh4.w * wr[k4*4+3];
        }
        out[(size_t)i * 64 + lane] = fmaxf(acc, 0.f);
    }
}

static inline size_t align512(size_t v) { return (v + 511) & ~(size_t)511; }

extern "C" void kernel_launch(void* const* d_in, const int* in_sizes, int n_in,
                              void* d_out, int out_size, void* d_ws, size_t ws_size,
                              hipStream_t stream) {
    const float* x    = (const float*)d_in[0];
    const int*   ei   = (const int*)d_in[1];
    const float* ew   = (const float*)d_in[2];
    const float* w1pl = (const float*)d_in[3];
    const float* w1pr = (const float*)d_in[4];
    const float* b1p  = (const float*)d_in[5];
    const float* w1nl = (const float*)d_in[6];
    const float* w1nr = (const float*)d_in[7];
    const float* b1n  = (const float*)d_in[8];
    const float* w2pl = (const float*)d_in[9];
    const float* w2pr = (const float*)d_in[10];
    const float* b2p  = (const float*)d_in[11];
    const float* w2nl = (const float*)d_in[12];
    const float* w2nr = (const float*)d_in[13];
    const float* b2n  = (const float*)d_in[14];

    const int N  = in_sizes[0] / 64;
    const int E  = in_sizes[2];
    const int nb = (N + 255) >> BSHIFT;      // 391 buckets (<=512 for N<=131072)

    char* ws = (char*)d_ws;
    size_t o = 0;
    int* bcnt   = (int*)(ws + o);      o += 512 * 4;
    int* gcur   = (int*)(ws + o);      size_t zero_end = o + 512 * 4;
                                       o = align512(zero_end);
    int* bbase  = (int*)(ws + o);      o = align512(o + 513 * 4);
    int* offs   = (int*)(ws + o);      o = align512(o + ((size_t)N + 1) * 4);
    int* pend   = (int*)(ws + o);      o = align512(o + (size_t)N * 4);
    float* rp   = (float*)(ws + o);    o = align512(o + (size_t)N * 4);
    float* rn   = (float*)(ws + o);    o = align512(o + (size_t)N * 4);
    u32* csr    = (u32*)(ws + o);      o = align512(o + (size_t)E * 4);
    // stage (E*4B) and cat (N*128*2B) have disjoint lifetimes -> union
    u32* stage  = (u32*)(ws + o);
    __half* cat = (__half*)(ws + o);
    {
        size_t stage_sz = (size_t)E * 4, cat_sz = (size_t)N * 256;
        o = align512(o + (stage_sz > cat_sz ? stage_sz : cat_sz));
    }
    __half* z1   = (__half*)(ws + o);  o = align512(o + (size_t)N * 128);
    __half* xr   = (__half*)(ws + o);  o = align512(o + (size_t)N * 128);
    __half* hbuf = (__half*)(ws + o);  o = align512(o + (size_t)N * 128);

    hipMemsetAsync(d_ws, 0, zero_end, stream);   // bcnt + gcur (4KB)

    k_bcnt <<<256, 512, 0, stream>>>(ei, ew, bcnt, E, nb);
    k_bscan<<<1, 512, 0, stream>>>(bcnt, bbase, offs + N, nb);
    k_bin  <<<(E + BIN_T * BIN_K - 1) / (BIN_T * BIN_K), BIN_T, 0, stream>>>(ei, ew, bbase, gcur, stage, E, nb);
    k_sort <<<nb, 256, 0, stream>>>(stage, bbase, csr, offs, pend, rp, rn, N);
    k_gemm1<<<1024, 256, 0, stream>>>(x, w1pl, w1pr, b1p, w1nl, w1nr, b1n, z1, xr, N);
    k_g1   <<<2048, 256, 0, stream>>>(z1, xr, offs, pend, rp, rn, csr, hbuf, N);
    k_g2a  <<<2048, 256, 0, stream>>>(hbuf, offs, pend, rp, rn, csr, cat, N);
    k_g2b  <<<1024, 256, 0, stream>>>(cat, hbuf, w2pl, w2pr, b2p, w2nl, w2nr, b2n,
                                      (float*)d_out, N);
}

// Round 5
// 187.865 us; speedup vs baseline: 3.9338x; 1.1587x over previous
//
#include <hip/hip_runtime.h>
#include <hip/hip_fp16.h>

typedef unsigned int u32;

#define BSHIFT 8                    // 256 nodes per bucket
#define BMASK  255

// ---------- helpers ----------
typedef _Float16 hf2 __attribute__((ext_vector_type(2)));
__device__ __forceinline__ float fdot2f(__half2 a, __half2 b, float c) {
#if __has_builtin(__builtin_amdgcn_fdot2)
    return __builtin_amdgcn_fdot2(*reinterpret_cast<hf2*>(&a), *reinterpret_cast<hf2*>(&b), c, false);
#else
    float2 fa = __half22float2(a), fb = __half22float2(b);
    return fmaf(fa.y, fb.y, fmaf(fa.x, fb.x, c));
#endif
}

__device__ __forceinline__ void acc_half8(float acc[8], const uint4 d) {
    const __half2* h = reinterpret_cast<const __half2*>(&d);
    #pragma unroll
    for (int q = 0; q < 4; ++q) {
        float2 f = __half22float2(h[q]);
        acc[2*q]   += f.x;
        acc[2*q+1] += f.y;
    }
}
__device__ __forceinline__ uint4 pack_half8(const float v[8], float s) {
    uint4 r;
    u32* p = &r.x;
    #pragma unroll
    for (int q = 0; q < 4; ++q) {
        __half2 h = __float22half2_rn(make_float2(v[2*q] * s, v[2*q+1] * s));
        p[q] = *reinterpret_cast<const u32*>(&h);
    }
    return r;
}

// ---------- 1) bucket counts (LDS-aggregated) ----------
__global__ __launch_bounds__(512) void k_bcnt(const int* __restrict__ ei, const float* __restrict__ ew,
                                              int* __restrict__ bcnt, int E, int nb) {
    __shared__ int lc[512];
    for (int i = threadIdx.x; i < nb; i += 512) lc[i] = 0;
    __syncthreads();
    const int stride = gridDim.x * 512;
    for (int e = blockIdx.x * 512 + threadIdx.x; e < E; e += stride) {
        float w = ew[e];
        if (w != 0.0f) atomicAdd(&lc[ei[E + e] >> BSHIFT], 1);
    }
    __syncthreads();
    for (int i = threadIdx.x; i < nb; i += 512) {
        int c = lc[i];
        if (c) atomicAdd(&bcnt[i], c);
    }
}

// ---------- 2) scan bucket counts -> bbase[nb+1], offs[N]=total ----------
__global__ __launch_bounds__(512) void k_bscan(const int* __restrict__ bcnt, int* __restrict__ bbase,
                                               int* __restrict__ offs_n, int nb) {
    __shared__ int wsum[8];
    const int t = threadIdx.x;
    const int lane = t & 63, wv = t >> 6;
    int v = (t < nb) ? bcnt[t] : 0;
    int s = v;
    #pragma unroll
    for (int off = 1; off < 64; off <<= 1) {
        int u = __shfl_up(s, off);
        if (lane >= off) s += u;
    }
    if (lane == 63) wsum[wv] = s;
    __syncthreads();
    if (t < 8) {
        int sv = wsum[t];
        #pragma unroll
        for (int off = 1; off < 8; off <<= 1) {
            int u = __shfl_up(sv, off);
            if (t >= off) sv += u;
        }
        wsum[t] = sv;
    }
    __syncthreads();
    int base = (wv ? wsum[wv - 1] : 0) + s - v;
    if (t < nb) bbase[t] = base;
    if (t == nb - 1) {
        bbase[nb] = base + v;
        *offs_n   = base + v;
    }
}

// ---------- 3) multi-split scatter into exact bucket regions ----------
#define BIN_T 512
#define BIN_K 16
__global__ __launch_bounds__(BIN_T) void k_bin(const int* __restrict__ ei, const float* __restrict__ ew,
                                               const int* __restrict__ bbase, int* __restrict__ gcur,
                                               u32* __restrict__ stage, int E, int nb) {
    __shared__ int lcnt[512];
    __shared__ int lbase[512];
    const int t = threadIdx.x;
    const int chunk = BIN_T * BIN_K;
    for (int c0 = blockIdx.x * chunk; c0 < E; c0 += gridDim.x * chunk) {
        for (int i = t; i < nb; i += BIN_T) lcnt[i] = 0;
        __syncthreads();
        u32 ent[BIN_K];
        int bk[BIN_K], loc[BIN_K];
        #pragma unroll
        for (int k = 0; k < BIN_K; ++k) {
            int e = c0 + k * BIN_T + t;
            bk[k] = -1;
            if (e < E) {
                float w = ew[e];
                if (w != 0.0f) {
                    int src = ei[e], dst = ei[E + e];
                    int b = dst >> BSHIFT;
                    bk[k]  = b;
                    ent[k] = (u32)src | ((u32)(dst & BMASK) << 17) | (w < 0.0f ? (1u << 25) : 0u);
                    loc[k] = atomicAdd(&lcnt[b], 1);
                }
            }
        }
        __syncthreads();
        for (int i = t; i < nb; i += BIN_T) {
            int c = lcnt[i];
            lbase[i] = c ? atomicAdd(&gcur[i], c) : 0;
        }
        __syncthreads();
        #pragma unroll
        for (int k = 0; k < BIN_K; ++k) {
            if (bk[k] >= 0) {
                int b = bk[k];
                stage[bbase[b] + lbase[b] + loc[k]] = ent[k];
            }
        }
        __syncthreads();
    }
}

// ---------- 4) per-bucket sort: csr + offs/pend/rp/rn ----------
__global__ __launch_bounds__(256) void k_sort(const u32* __restrict__ stage, const int* __restrict__ bbase,
                                              u32* __restrict__ csr,
                                              int* __restrict__ offs, int* __restrict__ pend,
                                              float* __restrict__ rp, float* __restrict__ rn,
                                              int N) {
    __shared__ int cnt[512];
    __shared__ int cbase[512];
    __shared__ int cur[512];
    const int b  = blockIdx.x;
    const int rb = bbase[b], re = bbase[b + 1];
    const int t  = threadIdx.x;
    cnt[t] = 0;
    cnt[t + 256] = 0;
    __syncthreads();
    for (int i = rb + t; i < re; i += 256) {
        u32 en = stage[i];
        atomicAdd(&cnt[((en >> 17) & BMASK) * 2 + ((en >> 25) & 1)], 1);
    }
    __syncthreads();
    if (t < 64) {
        int loc[8];
        int s = 0;
        #pragma unroll
        for (int q = 0; q < 8; ++q) { loc[q] = s; s += cnt[t * 8 + q]; }
        int tot = s;
        #pragma unroll
        for (int off = 1; off < 64; off <<= 1) {
            int u = __shfl_up(tot, off);
            if (t >= off) tot += u;
        }
        int excl = tot - s;
        #pragma unroll
        for (int q = 0; q < 8; ++q) {
            cbase[t * 8 + q] = excl + loc[q];
            cur  [t * 8 + q] = excl + loc[q];
        }
    }
    __syncthreads();
    const int gn = (b << BSHIFT) + t;
    if (gn < N) {
        int cp = cnt[2 * t], cng = cnt[2 * t + 1];
        int o  = rb + cbase[2 * t];
        offs[gn] = o;
        pend[gn] = o + cp;
        rp[gn] = 1.0f / (float)max(cp, 1);
        rn[gn] = 1.0f / (float)max(cng, 1);
    }
    for (int i = rb + t; i < re; i += 256) {
        u32 en  = stage[i];
        int key = ((en >> 17) & BMASK) * 2 + ((en >> 25) & 1);
        int slot = rb + atomicAdd(&cur[key], 1);
        csr[slot] = en & 0x1FFFFu;
    }
}

// ---------- dense transform 1 (fdot2): z1 = x@[w1pl||w1nl], xr = x@[w1pr||w1nr]+bias ----------
__global__ __launch_bounds__(256) void k_xf1(
    const float* __restrict__ x,
    const float* __restrict__ w1pl, const float* __restrict__ w1pr, const float* __restrict__ b1p,
    const float* __restrict__ w1nl, const float* __restrict__ w1nr, const float* __restrict__ b1n,
    __half* __restrict__ z1, __half* __restrict__ xr, int N)
{
    __shared__ __align__(16) __half2 s_x[64][32];     // 8 KB, 64-node tile
    const int t  = threadIdx.x;
    const int cc = t & 127;        // logical output column 0..127
    const int nh = t >> 7;         // node half
    const float* W; int c; float bias = 0.f;
    if (cc < 32)      { W = w1pl; c = cc; }
    else if (cc < 64) { W = w1nl; c = cc - 32; }
    else if (cc < 96) { W = w1pr; c = cc - 64; bias = b1p[c]; }
    else              { W = w1nr; c = cc - 96; bias = b1n[c]; }
    __half2 wv[32];
    #pragma unroll
    for (int j = 0; j < 32; ++j)
        wv[j] = __float22half2_rn(make_float2(W[(2*j)*32 + c], W[(2*j+1)*32 + c]));

    const float4* X4 = reinterpret_cast<const float4*>(x);
    __half2* sf = &s_x[0][0];
    for (int tile = blockIdx.x * 64; tile < N; tile += gridDim.x * 64) {
        const int nmax = min(64, N - tile);
        __syncthreads();
        for (int r = t; r < nmax * 16; r += 256) {
            float4 v = X4[(size_t)tile * 16 + r];
            sf[2*r]   = __float22half2_rn(make_float2(v.x, v.y));
            sf[2*r+1] = __float22half2_rn(make_float2(v.z, v.w));
        }
        __syncthreads();
        const int n0 = nh * 32, n1 = min(nmax, n0 + 32);
        for (int nn = n0; nn < n1; ++nn) {
            const uint4* row4 = reinterpret_cast<const uint4*>(s_x[nn]);
            float acc = bias;
            #pragma unroll
            for (int j4 = 0; j4 < 8; ++j4) {
                uint4 d = row4[j4];                      // b128 broadcast
                const __half2* p = reinterpret_cast<const __half2*>(&d);
                acc = fdot2f(p[0], wv[4*j4+0], acc);
                acc = fdot2f(p[1], wv[4*j4+1], acc);
                acc = fdot2f(p[2], wv[4*j4+2], acc);
                acc = fdot2f(p[3], wv[4*j4+3], acc);
            }
            __half hv = __float2half(acc);
            size_t n = (size_t)(tile + nn);
            if (cc < 64) z1[n * 64 + cc]        = hv;   // wave-uniform branch
            else         xr[n * 64 + (cc - 64)] = hv;
        }
    }
}

// ---------- gather 1: h = relu(xr + [mean_p || mean_n]) ----------
__global__ __launch_bounds__(256) void k_g1(
    const __half* __restrict__ z1, const __half* __restrict__ xr,
    const int* __restrict__ offs, const int* __restrict__ posend,
    const float* __restrict__ rpb, const float* __restrict__ rnb,
    const u32* __restrict__ csr, __half* __restrict__ h, int N)
{
    const int lane = threadIdx.x & 63;
    const int wv   = threadIdx.x >> 6;
    const int side = lane >> 5;
    const int g    = (lane & 31) >> 2;
    const int j    = lane & 3;
    const int hOff = side ? 32 : 0;

    const int gw = blockIdx.x * 4 + wv;
    const int nw = gridDim.x * 4;
    for (int i = gw; i < N; i += nw) {
        int beg = offs[i], pend_ = posend[i], end = offs[i + 1];
        int t    = (side ? pend_ : beg) + g;
        int send = side ? end : pend_;
        float acc[8] = {0,0,0,0,0,0,0,0};
        while (t < send) {
            u32 s0 = csr[t];
            uint4 d0 = *reinterpret_cast<const uint4*>(z1 + (size_t)s0 * 64 + hOff + j * 8);
            int t1 = t + 8;
            if (t1 < send) {
                u32 s1 = csr[t1];
                uint4 d1 = *reinterpret_cast<const uint4*>(z1 + (size_t)s1 * 64 + hOff + j * 8);
                acc_half8(acc, d0);
                acc_half8(acc, d1);
            } else {
                acc_half8(acc, d0);
            }
            t += 16;
        }
        #pragma unroll
        for (int m = 4; m <= 16; m <<= 1)
            #pragma unroll
            for (int q = 0; q < 8; ++q) acc[q] += __shfl_xor(acc[q], m);

        int wl = lane & 31;
        if (wl < 4) {
            float sc = side ? rnb[i] : rpb[i];
            uint4 xd = *reinterpret_cast<const uint4*>(xr + (size_t)i * 64 + hOff + wl * 8);
            const __half2* xh = reinterpret_cast<const __half2*>(&xd);
            float out[8];
            #pragma unroll
            for (int q = 0; q < 4; ++q) {
                float2 f = __half22float2(xh[q]);
                out[2*q]   = fmaxf(f.x + acc[2*q]   * sc, 0.f);
                out[2*q+1] = fmaxf(f.y + acc[2*q+1] * sc, 0.f);
            }
            *reinterpret_cast<uint4*>(h + (size_t)i * 64 + hOff + wl * 8) = pack_half8(out, 1.f);
        }
    }
}

// ---------- gather 2a: cat = [a1|a2|a3|a4] means (fp16) ----------
__global__ __launch_bounds__(256) void k_g2a(
    const __half* __restrict__ h,
    const int* __restrict__ offs, const int* __restrict__ posend,
    const float* __restrict__ rpb, const float* __restrict__ rnb,
    const u32* __restrict__ csr, __half* __restrict__ cat, int N)
{
    const int lane = threadIdx.x & 63;
    const int wv   = threadIdx.x >> 6;
    const int side = lane >> 5;
    const int g    = (lane & 31) >> 3;
    const int j    = lane & 7;

    const int gw = blockIdx.x * 4 + wv;
    const int nw = gridDim.x * 4;
    for (int i = gw; i < N; i += nw) {
        int beg = offs[i], pend_ = posend[i], end = offs[i + 1];
        int t    = (side ? pend_ : beg) + g;
        int send = side ? end : pend_;
        float acc[8] = {0,0,0,0,0,0,0,0};
        while (t < send) {
            u32 s0 = csr[t];
            uint4 d0 = *reinterpret_cast<const uint4*>(h + (size_t)s0 * 64 + j * 8);
            int t1 = t + 4;
            if (t1 < send) {
                u32 s1 = csr[t1];
                uint4 d1 = *reinterpret_cast<const uint4*>(h + (size_t)s1 * 64 + j * 8);
                acc_half8(acc, d0);
                acc_half8(acc, d1);
            } else {
                acc_half8(acc, d0);
            }
            t += 8;
        }
        #pragma unroll
        for (int m = 8; m <= 16; m <<= 1)
            #pragma unroll
            for (int q = 0; q < 8; ++q) acc[q] += __shfl_xor(acc[q], m);

        int wl = lane & 31;
        if (wl < 8) {
            float sc = side ? rnb[i] : rpb[i];
            int off = side ? (wl < 4 ? 96 + wl * 8 : 32 + (wl - 4) * 8)
                           : (wl < 4 ? wl * 8      : 64 + (wl - 4) * 8);
            *reinterpret_cast<uint4*>(cat + (size_t)i * 128 + off) = pack_half8(acc, sc);
        }
    }
}

// ---------- dense transform 2 (fdot2): out = relu(cat@W2L + h@W2R + b) ----------
__global__ __launch_bounds__(256) void k_xf2(
    const __half* __restrict__ cat, const __half* __restrict__ h,
    const float* __restrict__ w2pl, const float* __restrict__ w2pr, const float* __restrict__ b2p,
    const float* __restrict__ w2nl, const float* __restrict__ w2nr, const float* __restrict__ b2n,
    float* __restrict__ out, int N)
{
    __shared__ __align__(16) __half2 s_c[64][64];   // 16 KB
    __shared__ __align__(16) __half2 s_h[64][32];   // 8 KB
    const int t  = threadIdx.x;
    const int cc = t & 63;
    const int nq = t >> 6;
    const bool ng = cc >= 32;
    const float* WL = ng ? w2nl : w2pl;
    const float* WR = ng ? w2nr : w2pr;
    const int c = cc & 31;
    const float bias = (ng ? b2n : b2p)[c];
    __half2 wl[32], wr[16];
    #pragma unroll
    for (int j = 0; j < 32; ++j)
        wl[j] = __float22half2_rn(make_float2(WL[(2*j)*32 + c], WL[(2*j+1)*32 + c]));
    #pragma unroll
    for (int j = 0; j < 16; ++j)
        wr[j] = __float22half2_rn(make_float2(WR[(2*j)*32 + c], WR[(2*j+1)*32 + c]));

    const uint4* C4 = reinterpret_cast<const uint4*>(cat);
    const uint4* H4 = reinterpret_cast<const uint4*>(h);
    uint4* sc4 = reinterpret_cast<uint4*>(&s_c[0][0]);
    uint4* sh4 = reinterpret_cast<uint4*>(&s_h[0][0]);
    for (int tile = blockIdx.x * 64; tile < N; tile += gridDim.x * 64) {
        const int nmax = min(64, N - tile);
        __syncthreads();
        for (int r = t; r < nmax * 16; r += 256) sc4[r] = C4[(size_t)tile * 16 + r];
        for (int r = t; r < nmax * 8;  r += 256) sh4[r] = H4[(size_t)tile * 8 + r];
        __syncthreads();
        const int n0 = nq * 16, n1 = min(nmax, n0 + 16);
        for (int nn = n0; nn < n1; ++nn) {
            const uint4* c4 = reinterpret_cast<const uint4*>(&s_c[nn][ng ? 32 : 0]);
            const uint4* h4 = reinterpret_cast<const uint4*>(&s_h[nn][ng ? 16 : 0]);
            float acc = bias;
            #pragma unroll
            for (int j4 = 0; j4 < 8; ++j4) {
                uint4 d = c4[j4];
                const __half2* p = reinterpret_cast<const __half2*>(&d);
                acc = fdot2f(p[0], wl[4*j4+0], acc);
                acc = fdot2f(p[1], wl[4*j4+1], acc);
                acc = fdot2f(p[2], wl[4*j4+2], acc);
                acc = fdot2f(p[3], wl[4*j4+3], acc);
            }
            #pragma unroll
            for (int j4 = 0; j4 < 4; ++j4) {
                uint4 d = h4[j4];
                const __half2* p = reinterpret_cast<const __half2*>(&d);
                acc = fdot2f(p[0], wr[4*j4+0], acc);
                acc = fdot2f(p[1], wr[4*j4+1], acc);
                acc = fdot2f(p[2], wr[4*j4+2], acc);
                acc = fdot2f(p[3], wr[4*j4+3], acc);
            }
            out[(size_t)(tile + nn) * 64 + cc] = fmaxf(acc, 0.f);
        }
    }
}

static inline size_t align512(size_t v) { return (v + 511) & ~(size_t)511; }

extern "C" void kernel_launch(void* const* d_in, const int* in_sizes, int n_in,
                              void* d_out, int out_size, void* d_ws, size_t ws_size,
                              hipStream_t stream) {
    const float* x    = (const float*)d_in[0];
    const int*   ei   = (const int*)d_in[1];
    const float* ew   = (const float*)d_in[2];
    const float* w1pl = (const float*)d_in[3];
    const float* w1pr = (const float*)d_in[4];
    const float* b1p  = (const float*)d_in[5];
    const float* w1nl = (const float*)d_in[6];
    const float* w1nr = (const float*)d_in[7];
    const float* b1n  = (const float*)d_in[8];
    const float* w2pl = (const float*)d_in[9];
    const float* w2pr = (const float*)d_in[10];
    const float* b2p  = (const float*)d_in[11];
    const float* w2nl = (const float*)d_in[12];
    const float* w2nr = (const float*)d_in[13];
    const float* b2n  = (const float*)d_in[14];

    const int N  = in_sizes[0] / 64;
    const int E  = in_sizes[2];
    const int nb = (N + 255) >> BSHIFT;

    char* ws = (char*)d_ws;
    size_t o = 0;
    int* bcnt   = (int*)(ws + o);      o += 512 * 4;
    int* gcur   = (int*)(ws + o);      size_t zero_end = o + 512 * 4;
                                       o = align512(zero_end);
    int* bbase  = (int*)(ws + o);      o = align512(o + 513 * 4);
    int* offs   = (int*)(ws + o);      o = align512(o + ((size_t)N + 1) * 4);
    int* pend   = (int*)(ws + o);      o = align512(o + (size_t)N * 4);
    float* rp   = (float*)(ws + o);    o = align512(o + (size_t)N * 4);
    float* rn   = (float*)(ws + o);    o = align512(o + (size_t)N * 4);
    u32* csr    = (u32*)(ws + o);      o = align512(o + (size_t)E * 4);
    u32* stage  = (u32*)(ws + o);      // stage (E*4) and cat (N*256) union
    __half* cat = (__half*)(ws + o);
    {
        size_t stage_sz = (size_t)E * 4, cat_sz = (size_t)N * 256;
        o = align512(o + (stage_sz > cat_sz ? stage_sz : cat_sz));
    }
    __half* z1   = (__half*)(ws + o);  o = align512(o + (size_t)N * 128);
    __half* xr   = (__half*)(ws + o);  o = align512(o + (size_t)N * 128);
    __half* hbuf = (__half*)(ws + o);  o = align512(o + (size_t)N * 128);

    hipMemsetAsync(d_ws, 0, zero_end, stream);   // bcnt + gcur (4KB)

    const int nt = (N + 63) / 64;
    k_bcnt <<<256, 512, 0, stream>>>(ei, ew, bcnt, E, nb);
    k_bscan<<<1, 512, 0, stream>>>(bcnt, bbase, offs + N, nb);
    k_bin  <<<(E + BIN_T * BIN_K - 1) / (BIN_T * BIN_K), BIN_T, 0, stream>>>(ei, ew, bbase, gcur, stage, E, nb);
    k_sort <<<nb, 256, 0, stream>>>(stage, bbase, csr, offs, pend, rp, rn, N);
    k_xf1  <<<nt, 256, 0, stream>>>(x, w1pl, w1pr, b1p, w1nl, w1nr, b1n, z1, xr, N);
    k_g1   <<<2048, 256, 0, stream>>>(z1, xr, offs, pend, rp, rn, csr, hbuf, N);
    k_g2a  <<<2048, 256, 0, stream>>>(hbuf, offs, pend, rp, rn, csr, cat, N);
    k_xf2  <<<nt, 256, 0, stream>>>(cat, hbuf, w2pl, w2pr, b2p, w2nl, w2nr, b2n,
                                    (float*)d_out, N);
}